// Round 1
// baseline (2841.415 us; speedup 1.0000x reference)
//
#include <hip/hip_runtime.h>

#define RR 32
#define R3 (RR * RR * RR)         // 32768
#define BATCH 8
#define CH 64
#define NPTS 100000

// ---------------------------------------------------------------------------
// Path A accumulate: sums in [B, R3, C] layout (contiguous 256B per voxel),
// counts [B, R3]. One thread per point; c-loop reads are wave-coalesced
// (lane = consecutive n, fixed c), atomics per thread hit 4 cache lines.
// ---------------------------------------------------------------------------
__global__ __launch_bounds__(256) void accum_vc(
    const float* __restrict__ feat,    // [B, C, N]
    const float* __restrict__ coords,  // [B, 3, N]
    float* __restrict__ sums,          // [B, R3, C]
    unsigned int* __restrict__ cnt,    // [B, R3]
    float* __restrict__ out2)          // [B, 3, N] (voxel coords as float)
{
    int gid = blockIdx.x * blockDim.x + threadIdx.x;
    if (gid >= BATCH * NPTS) return;
    int b = gid / NPTS;
    int n = gid - b * NPTS;

    const float* cb = coords + (size_t)b * 3 * NPTS + n;
    float fx = fminf(fmaxf(cb[0]            * 32.0f, 0.0f), 31.0f);
    float fy = fminf(fmaxf(cb[NPTS]         * 32.0f, 0.0f), 31.0f);
    float fz = fminf(fmaxf(cb[2 * NPTS]     * 32.0f, 0.0f), 31.0f);
    int x = (int)rintf(fx);   // v_rndne_f32: round-half-even, matches jnp.round
    int y = (int)rintf(fy);
    int z = (int)rintf(fz);
    int v = x * (RR * RR) + y * RR + z;

    float* o2 = out2 + (size_t)b * 3 * NPTS + n;
    o2[0]        = (float)x;
    o2[NPTS]     = (float)y;
    o2[2 * NPTS] = (float)z;

    atomicAdd(&cnt[b * R3 + v], 1u);

    float* srow = sums + (size_t)(b * R3 + v) * CH;
    const float* frow = feat + (size_t)(b * CH) * NPTS + n;
#pragma unroll 8
    for (int c = 0; c < CH; ++c) {
        unsafeAtomicAdd(&srow[c], frow[(size_t)c * NPTS]);
    }
}

// ---------------------------------------------------------------------------
// Path A finalize: transpose [B, R3, C] -> [B, C, R3] with LDS tile,
// scaling by 1/max(cnt,1). Block = 256 threads, tile = 64 v x 64 c.
// ---------------------------------------------------------------------------
__global__ __launch_bounds__(256) void finalize_t(
    const float* __restrict__ sums,      // [B, R3, C]
    const unsigned int* __restrict__ cnt,// [B, R3]
    float* __restrict__ out)             // [B, C, R3]
{
    __shared__ float tile[64][65];   // +1 pad: transpose read is 2-way (free)
    __shared__ float rcp[64];

    int blk = blockIdx.x;                 // B * (R3/64) = 4096
    int b = blk / (R3 / 64);
    int v0 = (blk - b * (R3 / 64)) * 64;
    int tid = threadIdx.x;

    int c  = tid & 63;        // load phase: c fastest -> coalesced reads
    int vr = tid >> 6;        // 0..3
    const float* sbase = sums + (size_t)(b * R3 + v0) * CH;
#pragma unroll
    for (int i = 0; i < 64; i += 4) {
        tile[i + vr][c] = sbase[(size_t)(i + vr) * CH + c];
    }
    if (tid < 64) {
        unsigned int ct = cnt[b * R3 + v0 + tid];
        rcp[tid] = 1.0f / (float)(ct > 1u ? ct : 1u);
    }
    __syncthreads();

    int vv = tid & 63;        // store phase: v fastest -> coalesced writes
    int cr = tid >> 6;        // 0..3
    float* obase = out + (size_t)b * CH * R3 + v0;
    float r = rcp[vv];
#pragma unroll
    for (int j = 0; j < 64; j += 4) {
        obase[(size_t)(j + cr) * R3 + vv] = tile[vv][j + cr] * r;
    }
}

// ---------------------------------------------------------------------------
// Path B (fallback, small ws): accumulate straight into d_out [B, C, R3]
// (128KB-strided atomics), counts in ws; then divide in place.
// ---------------------------------------------------------------------------
__global__ __launch_bounds__(256) void accum_direct(
    const float* __restrict__ feat,
    const float* __restrict__ coords,
    float* __restrict__ out1,           // [B, C, R3]
    unsigned int* __restrict__ cnt,
    float* __restrict__ out2)
{
    int gid = blockIdx.x * blockDim.x + threadIdx.x;
    if (gid >= BATCH * NPTS) return;
    int b = gid / NPTS;
    int n = gid - b * NPTS;

    const float* cb = coords + (size_t)b * 3 * NPTS + n;
    float fx = fminf(fmaxf(cb[0]        * 32.0f, 0.0f), 31.0f);
    float fy = fminf(fmaxf(cb[NPTS]     * 32.0f, 0.0f), 31.0f);
    float fz = fminf(fmaxf(cb[2 * NPTS] * 32.0f, 0.0f), 31.0f);
    int x = (int)rintf(fx);
    int y = (int)rintf(fy);
    int z = (int)rintf(fz);
    int v = x * (RR * RR) + y * RR + z;

    float* o2 = out2 + (size_t)b * 3 * NPTS + n;
    o2[0]        = (float)x;
    o2[NPTS]     = (float)y;
    o2[2 * NPTS] = (float)z;

    atomicAdd(&cnt[b * R3 + v], 1u);

    float* obase = out1 + (size_t)(b * CH) * R3 + v;
    const float* frow = feat + (size_t)(b * CH) * NPTS + n;
#pragma unroll 8
    for (int c = 0; c < CH; ++c) {
        unsafeAtomicAdd(&obase[(size_t)c * R3], frow[(size_t)c * NPTS]);
    }
}

__global__ __launch_bounds__(256) void finalize_direct(
    float* __restrict__ out1,
    const unsigned int* __restrict__ cnt)
{
    size_t gid = (size_t)blockIdx.x * blockDim.x + threadIdx.x;
    size_t total = (size_t)BATCH * CH * R3;
    if (gid >= total) return;
    int v = (int)(gid & (R3 - 1));
    int b = (int)(gid / ((size_t)CH * R3));
    unsigned int ct = cnt[b * R3 + v];
    out1[gid] = out1[gid] / (float)(ct > 1u ? ct : 1u);
}

// ---------------------------------------------------------------------------
extern "C" void kernel_launch(void* const* d_in, const int* in_sizes, int n_in,
                              void* d_out, int out_size, void* d_ws, size_t ws_size,
                              hipStream_t stream)
{
    const float* feat   = (const float*)d_in[0];   // [8, 64, 100000]
    const float* coords = (const float*)d_in[1];   // [8, 3, 100000]

    float* out1 = (float*)d_out;                          // [8, 64, 32768]
    float* out2 = out1 + (size_t)BATCH * CH * R3;         // [8, 3, 100000]

    const size_t sums_bytes = (size_t)BATCH * R3 * CH * sizeof(float); // 64 MiB
    const size_t cnt_bytes  = (size_t)BATCH * R3 * sizeof(unsigned int); // 1 MiB

    const int npt_blocks = (BATCH * NPTS + 255) / 256;    // 3125

    if (ws_size >= sums_bytes + cnt_bytes) {
        float* sums = (float*)d_ws;
        unsigned int* cnt = (unsigned int*)((char*)d_ws + sums_bytes);
        hipMemsetAsync(d_ws, 0, sums_bytes + cnt_bytes, stream);
        accum_vc<<<npt_blocks, 256, 0, stream>>>(feat, coords, sums, cnt, out2);
        finalize_t<<<BATCH * (R3 / 64), 256, 0, stream>>>(sums, cnt, out1);
    } else {
        unsigned int* cnt = (unsigned int*)d_ws;
        hipMemsetAsync(out1, 0, sums_bytes, stream);
        hipMemsetAsync(d_ws, 0, cnt_bytes, stream);
        accum_direct<<<npt_blocks, 256, 0, stream>>>(feat, coords, out1, cnt, out2);
        size_t total = (size_t)BATCH * CH * R3;
        finalize_direct<<<(unsigned)((total + 255) / 256), 256, 0, stream>>>(out1, cnt);
    }
}

// Round 2
// 498.832 us; speedup vs baseline: 5.6961x; 5.6961x over previous
//
#include <hip/hip_runtime.h>

#define RR 32
#define R3 32768
#define BATCH 8
#define CH 64
#define NPTS 100000
#define NPOINTS (BATCH * NPTS)   // 800000
#define NVOX (BATCH * R3)        // 262144
#define SCAN_BLOCKS (NVOX / 256) // 1024

typedef unsigned int uint32;

__device__ __forceinline__ uint32 f2bf(float f) {
    uint32 u = __float_as_uint(f);
    return (u + 0x7fffu + ((u >> 16) & 1u)) >> 16;   // RNE to bf16
}
__device__ __forceinline__ float bf2f(uint32 h) {
    return __uint_as_float(h << 16);
}

// ---------------------------------------------------------------------------
// Phase 1: voxel id per point + histogram + coords output.
// ---------------------------------------------------------------------------
__global__ __launch_bounds__(256) void phase1_count(
    const float* __restrict__ coords,  // [B, 3, N]
    uint32* __restrict__ vox,          // [NPOINTS] global voxel id
    uint32* __restrict__ cnt,          // [NVOX] (pre-zeroed)
    float* __restrict__ out2)          // [B, 3, N] voxel coords as float
{
    int gid = blockIdx.x * blockDim.x + threadIdx.x;
    if (gid >= NPOINTS) return;
    int b = gid / NPTS;
    int n = gid - b * NPTS;

    const float* cb = coords + (size_t)b * 3 * NPTS + n;
    float fx = fminf(fmaxf(cb[0]        * 32.0f, 0.0f), 31.0f);
    float fy = fminf(fmaxf(cb[NPTS]     * 32.0f, 0.0f), 31.0f);
    float fz = fminf(fmaxf(cb[2 * NPTS] * 32.0f, 0.0f), 31.0f);
    int x = (int)rintf(fx);   // round-half-even matches jnp.round
    int y = (int)rintf(fy);
    int z = (int)rintf(fz);
    uint32 g = (uint32)(b * R3 + x * (RR * RR) + y * RR + z);

    float* o2 = out2 + (size_t)b * 3 * NPTS + n;
    o2[0]        = (float)x;
    o2[NPTS]     = (float)y;
    o2[2 * NPTS] = (float)z;

    vox[gid] = g;
    atomicAdd(&cnt[g], 1u);
}

// ---------------------------------------------------------------------------
// Phase 2: exclusive scan over cnt[NVOX] -> starts[], cursor[] (3 kernels).
// ---------------------------------------------------------------------------
__global__ __launch_bounds__(256) void scan_block_sums(
    const uint32* __restrict__ cnt, uint32* __restrict__ bsum)
{
    __shared__ uint32 s[256];
    int t = threadIdx.x;
    s[t] = cnt[blockIdx.x * 256 + t];
    __syncthreads();
    for (int off = 128; off > 0; off >>= 1) {
        if (t < off) s[t] += s[t + off];
        __syncthreads();
    }
    if (t == 0) bsum[blockIdx.x] = s[0];
}

__global__ __launch_bounds__(256) void scan_bsum(uint32* __restrict__ bsum)
{
    __shared__ uint32 s[256];
    int t = threadIdx.x;
    uint32 v0 = bsum[4 * t], v1 = bsum[4 * t + 1], v2 = bsum[4 * t + 2], v3 = bsum[4 * t + 3];
    uint32 tot = v0 + v1 + v2 + v3;
    s[t] = tot;
    __syncthreads();
    for (int off = 1; off < 256; off <<= 1) {
        uint32 x = (t >= off) ? s[t - off] : 0u;
        __syncthreads();
        s[t] += x;
        __syncthreads();
    }
    uint32 excl = s[t] - tot;
    bsum[4 * t]     = excl;
    bsum[4 * t + 1] = excl + v0;
    bsum[4 * t + 2] = excl + v0 + v1;
    bsum[4 * t + 3] = excl + v0 + v1 + v2;
}

__global__ __launch_bounds__(256) void scan_final(
    const uint32* __restrict__ cnt, const uint32* __restrict__ bsum,
    uint32* __restrict__ starts, uint32* __restrict__ cursor)
{
    __shared__ uint32 s[256];
    int t = threadIdx.x;
    int gid = blockIdx.x * 256 + t;
    uint32 v = cnt[gid];
    s[t] = v;
    __syncthreads();
    for (int off = 1; off < 256; off <<= 1) {
        uint32 x = (t >= off) ? s[t - off] : 0u;
        __syncthreads();
        s[t] += x;
        __syncthreads();
    }
    uint32 st = bsum[blockIdx.x] + s[t] - v;   // exclusive
    starts[gid] = st;
    cursor[gid] = st;
}

// ---------------------------------------------------------------------------
// Phase 3: scatter features (bf16x2 packed, 128 B/point) into voxel order.
// Reads coalesced (lane = consecutive n, fixed c); writes full 128 B blocks.
// ---------------------------------------------------------------------------
__global__ __launch_bounds__(256) void phase3_scatter(
    const float* __restrict__ feat,    // [B, C, N]
    const uint32* __restrict__ vox,
    uint32* __restrict__ cursor,
    uint4* __restrict__ sorted)        // [NPOINTS][8] uint4 (= 64 bf16 ch)
{
    int gid = blockIdx.x * blockDim.x + threadIdx.x;
    if (gid >= NPOINTS) return;
    int b = gid / NPTS;
    int n = gid - b * NPTS;

    uint32 g = vox[gid];
    uint32 pos = atomicAdd(&cursor[g], 1u);

    const float* frow = feat + (size_t)b * CH * NPTS + n;
    uint4* dst = sorted + (size_t)pos * 8;
#pragma unroll
    for (int j = 0; j < 8; ++j) {
        uint4 w;
        float f0 = frow[(size_t)(8 * j + 0) * NPTS];
        float f1 = frow[(size_t)(8 * j + 1) * NPTS];
        float f2 = frow[(size_t)(8 * j + 2) * NPTS];
        float f3 = frow[(size_t)(8 * j + 3) * NPTS];
        float f4 = frow[(size_t)(8 * j + 4) * NPTS];
        float f5 = frow[(size_t)(8 * j + 5) * NPTS];
        float f6 = frow[(size_t)(8 * j + 6) * NPTS];
        float f7 = frow[(size_t)(8 * j + 7) * NPTS];
        w.x = f2bf(f0) | (f2bf(f1) << 16);
        w.y = f2bf(f2) | (f2bf(f3) << 16);
        w.z = f2bf(f4) | (f2bf(f5) << 16);
        w.w = f2bf(f6) | (f2bf(f7) << 16);
        dst[j] = w;
    }
}

// ---------------------------------------------------------------------------
// Phase 4: per-block reduce of 64 consecutive voxels (contiguous segment),
// LDS transpose, coalesced [B,C,R3] write with fused divide.
// ---------------------------------------------------------------------------
__global__ __launch_bounds__(256) void phase4_reduce(
    const uint32* __restrict__ sorted,   // [NPOINTS][32] uint (bf16x2)
    const uint32* __restrict__ starts,
    float* __restrict__ out1)            // [B, C, R3]
{
    __shared__ float tile[64][65];

    int gbase = blockIdx.x * 64;       // global voxel base
    int tid = threadIdx.x;
    int wave = tid >> 6, lane = tid & 63;

    if (lane < 32) {
        for (int k = 0; k < 16; ++k) {
            int g = gbase + wave * 16 + k;
            uint32 s = starts[g];
            uint32 e = (g == NVOX - 1) ? (uint32)NPOINTS : starts[g + 1];
            float a0 = 0.0f, a1 = 0.0f;
            for (uint32 p = s; p < e; ++p) {
                uint32 w = sorted[(size_t)p * 32 + lane];
                a0 += bf2f(w & 0xffffu);
                a1 += bf2f(w >> 16);
            }
            uint32 c = e - s;
            float rcp = 1.0f / (float)(c > 1u ? c : 1u);
            int vloc = wave * 16 + k;
            tile[vloc][2 * lane]     = a0 * rcp;
            tile[vloc][2 * lane + 1] = a1 * rcp;
        }
    }
    __syncthreads();

    int b = gbase / R3;
    int v0 = gbase - b * R3;
    int vv = tid & 63;
    int c0 = tid >> 6;
    float* obase = out1 + (size_t)b * CH * R3 + v0 + vv;
#pragma unroll
    for (int jj = 0; jj < 16; ++jj) {
        int c = jj * 4 + c0;
        obase[(size_t)c * R3] = tile[vv][c];
    }
}

// ---------------------------------------------------------------------------
// Fallback paths (small ws): previous round's atomic kernels.
// ---------------------------------------------------------------------------
__global__ __launch_bounds__(256) void accum_direct(
    const float* __restrict__ feat, const float* __restrict__ coords,
    float* __restrict__ out1, uint32* __restrict__ cnt, float* __restrict__ out2)
{
    int gid = blockIdx.x * blockDim.x + threadIdx.x;
    if (gid >= NPOINTS) return;
    int b = gid / NPTS;
    int n = gid - b * NPTS;
    const float* cb = coords + (size_t)b * 3 * NPTS + n;
    float fx = fminf(fmaxf(cb[0]        * 32.0f, 0.0f), 31.0f);
    float fy = fminf(fmaxf(cb[NPTS]     * 32.0f, 0.0f), 31.0f);
    float fz = fminf(fmaxf(cb[2 * NPTS] * 32.0f, 0.0f), 31.0f);
    int x = (int)rintf(fx), y = (int)rintf(fy), z = (int)rintf(fz);
    int v = x * (RR * RR) + y * RR + z;
    float* o2 = out2 + (size_t)b * 3 * NPTS + n;
    o2[0] = (float)x; o2[NPTS] = (float)y; o2[2 * NPTS] = (float)z;
    atomicAdd(&cnt[b * R3 + v], 1u);
    float* obase = out1 + (size_t)(b * CH) * R3 + v;
    const float* frow = feat + (size_t)(b * CH) * NPTS + n;
#pragma unroll 8
    for (int c = 0; c < CH; ++c)
        unsafeAtomicAdd(&obase[(size_t)c * R3], frow[(size_t)c * NPTS]);
}

__global__ __launch_bounds__(256) void finalize_direct(
    float* __restrict__ out1, const uint32* __restrict__ cnt)
{
    size_t gid = (size_t)blockIdx.x * blockDim.x + threadIdx.x;
    size_t total = (size_t)BATCH * CH * R3;
    if (gid >= total) return;
    int v = (int)(gid & (R3 - 1));
    int b = (int)(gid / ((size_t)CH * R3));
    uint32 ct = cnt[b * R3 + v];
    out1[gid] = out1[gid] / (float)(ct > 1u ? ct : 1u);
}

// ---------------------------------------------------------------------------
extern "C" void kernel_launch(void* const* d_in, const int* in_sizes, int n_in,
                              void* d_out, int out_size, void* d_ws, size_t ws_size,
                              hipStream_t stream)
{
    const float* feat   = (const float*)d_in[0];   // [8, 64, 100000]
    const float* coords = (const float*)d_in[1];   // [8, 3, 100000]

    float* out1 = (float*)d_out;                          // [8, 64, 32768]
    float* out2 = out1 + (size_t)BATCH * CH * R3;         // [8, 3, 100000]

    // ws layout for sort path
    const size_t vox_off    = 0;
    const size_t vox_bytes  = (size_t)NPOINTS * 4;                 // 3.2 MB
    const size_t cnt_off    = vox_off + ((vox_bytes + 255) & ~255ull);
    const size_t cnt_bytes  = (size_t)NVOX * 4;                    // 1 MB
    const size_t starts_off = cnt_off + ((cnt_bytes + 255) & ~255ull);
    const size_t cursor_off = starts_off + ((cnt_bytes + 255) & ~255ull);
    const size_t bsum_off   = cursor_off + ((cnt_bytes + 255) & ~255ull);
    const size_t bsum_bytes = (size_t)SCAN_BLOCKS * 4;
    const size_t sort_off   = (bsum_off + bsum_bytes + 255) & ~255ull;
    const size_t sort_bytes = (size_t)NPOINTS * 128;               // 102.4 MB
    const size_t need       = sort_off + sort_bytes;

    const int npt_blocks = (NPOINTS + 255) / 256;   // 3125

    if (ws_size >= need) {
        char* ws = (char*)d_ws;
        uint32* vox    = (uint32*)(ws + vox_off);
        uint32* cnt    = (uint32*)(ws + cnt_off);
        uint32* starts = (uint32*)(ws + starts_off);
        uint32* cursor = (uint32*)(ws + cursor_off);
        uint32* bsum   = (uint32*)(ws + bsum_off);
        uint32* sorted = (uint32*)(ws + sort_off);

        hipMemsetAsync(cnt, 0, cnt_bytes, stream);
        phase1_count<<<npt_blocks, 256, 0, stream>>>(coords, vox, cnt, out2);
        scan_block_sums<<<SCAN_BLOCKS, 256, 0, stream>>>(cnt, bsum);
        scan_bsum<<<1, 256, 0, stream>>>(bsum);
        scan_final<<<SCAN_BLOCKS, 256, 0, stream>>>(cnt, bsum, starts, cursor);
        phase3_scatter<<<npt_blocks, 256, 0, stream>>>(feat, vox, cursor, (uint4*)sorted);
        phase4_reduce<<<NVOX / 64, 256, 0, stream>>>(sorted, starts, out1);
    } else {
        // fallback: direct atomic accumulate into d_out
        uint32* cnt = (uint32*)d_ws;
        hipMemsetAsync(out1, 0, (size_t)BATCH * CH * R3 * sizeof(float), stream);
        hipMemsetAsync(d_ws, 0, (size_t)NVOX * 4, stream);
        accum_direct<<<npt_blocks, 256, 0, stream>>>(feat, coords, out1, cnt, out2);
        size_t total = (size_t)BATCH * CH * R3;
        finalize_direct<<<(unsigned)((total + 255) / 256), 256, 0, stream>>>(out1, cnt);
    }
}